// Round 2
// baseline (516.552 us; speedup 1.0000x reference)
//
#include <hip/hip_runtime.h>
#include <cstdint>
#include <cstddef>

// Problem constants (fixed by reference setup)
#define B_   16
#define M_   512
#define HID_ 768
#define NH_  12
#define HD_  64

typedef short s16x8 __attribute__((ext_vector_type(8)));
typedef float f32x4 __attribute__((ext_vector_type(4)));

__device__ __forceinline__ unsigned short f2bf(float f) {
    unsigned int u = __builtin_bit_cast(unsigned int, f);
    u = u + 0x7FFFu + ((u >> 16) & 1u);   // RNE truncate to bf16
    return (unsigned short)(u >> 16);
}

// ---------------------------------------------------------------------------
// Kernel 1: Q = X @ Wq + bq   (8192 x 768 = [B*M, HID]), bf16 MFMA 16x16x32.
// Block = 256 threads (4 waves), tile 128x128, BK=32. Grid (768/128, 8192/128).
// ---------------------------------------------------------------------------
__launch_bounds__(256)
__global__ void gemm_q(const float* __restrict__ X, const float* __restrict__ W,
                       const float* __restrict__ bq, float* __restrict__ Q) {
    __shared__ unsigned short As[128][40];   // [m][k], +8 pad
    __shared__ unsigned short Bs[128][40];   // [n][k] (transposed), +8 pad

    const int tid  = threadIdx.x;
    const int lane = tid & 63;
    const int wave = tid >> 6;
    const int wr   = (wave >> 1) * 64;
    const int wc   = (wave & 1) * 64;
    const int ln   = lane & 15;
    const int quad = lane >> 4;
    const int q8   = quad * 8;
    const int r0   = blockIdx.y * 128;
    const int n0   = blockIdx.x * 128;

    f32x4 acc[4][4] = {};

    for (int kt = 0; kt < HID_ / 32; ++kt) {
        const int k0 = kt * 32;
        // stage A: rows r0..r0+127, cols k0..k0+31 (fp32 -> bf16)
        #pragma unroll
        for (int p = 0; p < 4; ++p) {
            int t = tid + p * 256;
            int row = t >> 3;
            int kk  = (t & 7) * 4;
            const float4 v = *(const float4*)(X + (size_t)(r0 + row) * HID_ + k0 + kk);
            As[row][kk + 0] = f2bf(v.x);
            As[row][kk + 1] = f2bf(v.y);
            As[row][kk + 2] = f2bf(v.z);
            As[row][kk + 3] = f2bf(v.w);
        }
        // stage B transposed: W[k0+kr][n0+nn..+3] -> Bs[nn..][kr]
        #pragma unroll
        for (int p = 0; p < 4; ++p) {
            int t = tid + p * 256;
            int kr = t >> 5;
            int nn = (t & 31) * 4;
            const float4 v = *(const float4*)(W + (size_t)(k0 + kr) * HID_ + n0 + nn);
            Bs[nn + 0][kr] = f2bf(v.x);
            Bs[nn + 1][kr] = f2bf(v.y);
            Bs[nn + 2][kr] = f2bf(v.z);
            Bs[nn + 3][kr] = f2bf(v.w);
        }
        __syncthreads();

        s16x8 af[4], bf[4];
        #pragma unroll
        for (int r = 0; r < 4; ++r)
            af[r] = *(const s16x8*)&As[wr + r * 16 + ln][q8];
        #pragma unroll
        for (int c = 0; c < 4; ++c)
            bf[c] = *(const s16x8*)&Bs[wc + c * 16 + ln][q8];
        #pragma unroll
        for (int r = 0; r < 4; ++r)
            #pragma unroll
            for (int c = 0; c < 4; ++c)
                acc[r][c] = __builtin_amdgcn_mfma_f32_16x16x32_bf16(af[r], bf[c], acc[r][c], 0, 0, 0);
        __syncthreads();
    }

    // epilogue: C/D layout col=lane&15, row=quad*4+reg  [m89-verified]
    #pragma unroll
    for (int c = 0; c < 4; ++c) {
        const int col = n0 + wc + c * 16 + ln;
        const float bias = bq[col];
        #pragma unroll
        for (int r = 0; r < 4; ++r) {
            const int rowb = r0 + wr + r * 16 + quad * 4;
            #pragma unroll
            for (int e = 0; e < 4; ++e)
                Q[(size_t)(rowb + e) * HID_ + col] = acc[r][c][e] + bias;
        }
    }
}

// ---------------------------------------------------------------------------
// Kernel 2: per-(b,h) row stats. 192 blocks x 512 threads (thread = row i).
//  - s_next[i] = q_i . q_{i+1} / 64
//  - 2-way masked softmax -> p_prev/p_next  (assumes >=1 valid neighbor/row,
//    true for the reference all-ones mask)
//  - sym, na_super (i,i+1), na_sub (i+1,i) incl. prior blend
//  - S = exclusive prefix sum of log(na_super + 1e-9)
// ---------------------------------------------------------------------------
__launch_bounds__(512)
__global__ void rowstats(const float* __restrict__ Q, const float* __restrict__ prior,
                         const int* __restrict__ mask,
                         float* __restrict__ na_super, float* __restrict__ na_sub,
                         float* __restrict__ Ssum) {
    const int bh = blockIdx.x;
    const int b  = bh / NH_;
    const int h  = bh - b * NH_;
    const int i  = threadIdx.x;

    __shared__ float sh_s[M_];
    __shared__ float sh_pp[M_];
    __shared__ float sc[2][M_];

    float s = 0.f;
    if (i < M_ - 1) {
        const float4* qa = (const float4*)(Q + (size_t)(b * M_ + i)     * HID_ + h * HD_);
        const float4* qb = (const float4*)(Q + (size_t)(b * M_ + i + 1) * HID_ + h * HD_);
        #pragma unroll
        for (int t = 0; t < 16; ++t) {
            float4 x = qa[t], y = qb[t];
            s += x.x * y.x + x.y * y.y + x.z * y.z + x.w * y.w;
        }
        s *= (1.f / 64.f);
    }
    sh_s[i] = s;
    __syncthreads();

    const bool vp = (i > 0)      && (mask[b * M_ + i - 1] > 0);
    const bool vn = (i < M_ - 1) && (mask[b * M_ + i + 1] > 0);
    const float sp = vp ? sh_s[i - 1] : -1e30f;
    const float sn = vn ? s : -1e30f;
    const float mx = fmaxf(sp, sn);
    const float ep = vp ? __expf(sp - mx) : 0.f;
    const float en = vn ? __expf(sn - mx) : 0.f;
    float den = ep + en;
    den = (den > 0.f) ? den : 1.f;
    const float pp = ep / den;
    const float pn = en / den;
    sh_pp[i] = pp;
    __syncthreads();

    float Lv = 0.f;
    if (i < M_ - 1) {
        const float  sym = sqrtf(pn * sh_pp[i + 1] + 1e-4f);
        const size_t pb  = (size_t)b * (M_ * M_);
        const float  prs = prior[pb + (size_t)i * M_ + (i + 1)];
        const float  prb = prior[pb + (size_t)(i + 1) * M_ + i];
        const float  nsup = prs + (1.f - prs) * sym;
        na_super[bh * M_ + i] = nsup;
        na_sub[bh * M_ + i]   = prb + (1.f - prb) * sym;
        Lv = logf(nsup + 1e-9f);
    }

    // Hillis-Steele inclusive scan (double-buffered), then shift for exclusive
    int pbuf = 0;
    sc[0][i] = Lv;
    __syncthreads();
    for (int off = 1; off < M_; off <<= 1) {
        float v = sc[pbuf][i] + ((i >= off) ? sc[pbuf][i - off] : 0.f);
        sc[pbuf ^ 1][i] = v;
        __syncthreads();
        pbuf ^= 1;
    }
    Ssum[bh * M_ + i] = (i > 0) ? sc[pbuf][i - 1] : 0.f;
}

// ---------------------------------------------------------------------------
// Kernel 3: dense fill of both outputs. Block = 256 threads = 2 rows x 512
// cols (float4/lane). Block order (b, i, h) so the 12 h-copies of a prior row
// are adjacent in dispatch (L2 locality). Nontemporal stores (write-once).
// ---------------------------------------------------------------------------
__launch_bounds__(256)
__global__ void fill_out(const float* __restrict__ prior,
                         const float* __restrict__ na_super,
                         const float* __restrict__ na_sub,
                         const float* __restrict__ Ssum,
                         float* __restrict__ out) {
    const int tid = threadIdx.x;
    const int idx = blockIdx.x * 2 + (tid >> 7);       // 0..98303, order (b,i,h)
    const int h   = idx % NH_;
    const int tmp = idx / NH_;                         // b*512 + i
    const int i   = tmp & (M_ - 1);
    const int b   = tmp >> 9;
    const int bh  = b * NH_ + h;
    const int j0  = (tid & 127) * 4;

    const float4 pr4 = *(const float4*)(prior + (size_t)b * (M_ * M_) + (size_t)i * M_ + j0);
    const float4 S4  = *(const float4*)(Ssum + bh * M_ + j0);
    const float  Si  = Ssum[bh * M_ + i];
    const float  nsup_i   = (i < M_ - 1) ? na_super[bh * M_ + i]     : 0.f;
    const float  nsub_im1 = (i > 0)      ? na_sub[bh * M_ + i - 1]   : 0.f;

    const float c0 = 0.00999999977f;   // sqrtf(1e-4f), the off-neighbor V value

    const float pv[4] = {pr4.x, pr4.y, pr4.z, pr4.w};
    const float sv[4] = {S4.x, S4.y, S4.z, S4.w};
    float nav[4], ggv[4];
    #pragma unroll
    for (int e = 0; e < 4; ++e) {
        const int j = j0 + e;
        float na = fmaf(pv[e], 1.f - c0, c0);          // prior + (1-prior)*c0
        if (j == i - 1) na = nsub_im1;
        if (j == i + 1) na = nsup_i;
        const float d = sv[e] - Si;
        float g = __expf((j > i) ? d : -d) + 1e-4f;    // exp(S[max]-S[min]) + EPS
        if (j == i) g = na;                            // diag: neibor_attn[i,i]
        nav[e] = na;
        ggv[e] = g;
    }

    const size_t off  = ((size_t)(bh * M_ + i)) * M_ + j0;
    const size_t half = (size_t)B_ * NH_ * M_ * M_;    // 50331648
    f32x4 g4 = {ggv[0], ggv[1], ggv[2], ggv[3]};
    f32x4 n4 = {nav[0], nav[1], nav[2], nav[3]};
    __builtin_nontemporal_store(g4, (f32x4*)(out + off));         // g_attn
    __builtin_nontemporal_store(n4, (f32x4*)(out + half + off));  // neibor_attn
}

// ---------------------------------------------------------------------------
extern "C" void kernel_launch(void* const* d_in, const int* in_sizes, int n_in,
                              void* d_out, int out_size, void* d_ws, size_t ws_size,
                              hipStream_t stream) {
    const float* X     = (const float*)d_in[0];   // (B, M, HID)
    const float* prior = (const float*)d_in[1];   // (B, 1, M, M)
    const float* Wq    = (const float*)d_in[2];   // (HID, HID)
    const float* bq    = (const float*)d_in[3];   // (HID,)
    const int*   msk   = (const int*)  d_in[4];   // (B, M)
    float* out = (float*)d_out;

    // workspace layout (floats): Q | na_super | na_sub | Ssum  (~26.3 MB)
    float* Q        = (float*)d_ws;
    float* na_super = Q + (size_t)B_ * M_ * HID_;          // 6,291,456
    float* na_sub   = na_super + (size_t)B_ * NH_ * M_;    //   98,304
    float* Ssum     = na_sub   + (size_t)B_ * NH_ * M_;    //   98,304

    dim3 gg(HID_ / 128, (B_ * M_) / 128);                  // (6, 64)
    gemm_q<<<gg, 256, 0, stream>>>(X, Wq, bq, Q);

    rowstats<<<B_ * NH_, M_, 0, stream>>>(Q, prior, msk, na_super, na_sub, Ssum);

    fill_out<<<(B_ * NH_ * M_) / 2, 256, 0, stream>>>(prior, na_super, na_sub, Ssum, out);
}

// Round 3
// 484.736 us; speedup vs baseline: 1.0656x; 1.0656x over previous
//
#include <hip/hip_runtime.h>
#include <cstdint>
#include <cstddef>

// Problem constants (fixed by reference setup)
#define B_   16
#define M_   512
#define HID_ 768
#define NH_  12
#define HD_  64

typedef short s16x8 __attribute__((ext_vector_type(8)));
typedef float f32x4 __attribute__((ext_vector_type(4)));
typedef unsigned short u16x8 __attribute__((ext_vector_type(8)));
typedef unsigned short u16x4 __attribute__((ext_vector_type(4)));

__device__ __forceinline__ unsigned short f2bf(float f) {
    unsigned int u = __builtin_bit_cast(unsigned int, f);
    u = u + 0x7FFFu + ((u >> 16) & 1u);   // RNE truncate to bf16
    return (unsigned short)(u >> 16);
}

// async global->LDS, 16 B per lane; lds dest = wave-uniform base + lane*16
__device__ __forceinline__ void gld_lds16(const void* g, void* lds) {
    __builtin_amdgcn_global_load_lds(
        (const __attribute__((address_space(1))) unsigned int*)g,
        (__attribute__((address_space(3))) unsigned int*)lds,
        16, 0, 0);
}

// ---------------------------------------------------------------------------
// Pre-pass A: X (B*M, HID) fp32 -> bf16 row-major. 8 floats/thread.
// ---------------------------------------------------------------------------
__launch_bounds__(256)
__global__ void convert_x(const float* __restrict__ X, unsigned short* __restrict__ Xb) {
    const size_t i = ((size_t)blockIdx.x * 256 + threadIdx.x) * 8;
    const float4 a = *(const float4*)(X + i);
    const float4 b = *(const float4*)(X + i + 4);
    u16x8 v = { f2bf(a.x), f2bf(a.y), f2bf(a.z), f2bf(a.w),
                f2bf(b.x), f2bf(b.y), f2bf(b.z), f2bf(b.w) };
    *(u16x8*)(Xb + i) = v;
}

// ---------------------------------------------------------------------------
// Pre-pass B: W (K=768, N=768) fp32 -> bf16 transposed Wt[n][k]. 32x32 tiles.
// ---------------------------------------------------------------------------
__launch_bounds__(256)
__global__ void transpose_w(const float* __restrict__ W, unsigned short* __restrict__ Wt) {
    __shared__ float T[32][33];
    const int t  = threadIdx.x;
    const int n0 = blockIdx.x * 32;
    const int k0 = blockIdx.y * 32;
    #pragma unroll
    for (int p = 0; p < 4; ++p) {
        const int r = p * 8 + (t >> 5);   // k_local
        const int c = t & 31;             // n_local
        T[r][c] = W[(size_t)(k0 + r) * HID_ + n0 + c];
    }
    __syncthreads();
    const int nl = t >> 3;                // 0..31
    const int k4 = (t & 7) * 4;
    u16x4 v = { f2bf(T[k4 + 0][nl]), f2bf(T[k4 + 1][nl]),
                f2bf(T[k4 + 2][nl]), f2bf(T[k4 + 3][nl]) };
    *(u16x4*)(Wt + (size_t)(n0 + nl) * HID_ + k0 + k4) = v;
}

// ---------------------------------------------------------------------------
// Kernel 1: Q = X @ Wq + bq  via bf16 MFMA 16x16x32, m97-style staging.
// Tile 128x128, BK=32, 4 waves. A: Xb[M][K], B: Wt[N][K] (both bf16 row-major,
// 64 B per K-tile row, unpadded -- required by global_load_lds lane layout).
// ---------------------------------------------------------------------------
__launch_bounds__(256)
__global__ void gemm_qb(const unsigned short* __restrict__ Xb,
                        const unsigned short* __restrict__ Wt,
                        const float* __restrict__ bq, float* __restrict__ Q) {
    __shared__ unsigned short As[128 * 32];   // row*64B + kbyte
    __shared__ unsigned short Bs[128 * 32];

    const int tid  = threadIdx.x;
    const int lane = tid & 63;
    const int wave = tid >> 6;
    const int wr   = (wave >> 1) * 64;
    const int wc   = (wave & 1) * 64;
    const int ln   = lane & 15;
    const int quad = lane >> 4;
    const int r0   = blockIdx.y * 128;
    const int n0   = blockIdx.x * 128;

    // staging geometry: chunk = 16 rows = 1024 B; lane -> row lane>>2, 16B piece lane&3
    const int srow  = lane >> 2;
    const int skoff = (lane & 3) * 8;         // bf16 elems within 32-elem row

    f32x4 acc[4][4] = {};

    for (int kt = 0; kt < HID_ / 32; ++kt) {
        const int k0 = kt * 32;
        #pragma unroll
        for (int c = wave * 2; c < wave * 2 + 2; ++c) {
            const unsigned short* ga = Xb + (size_t)(r0 + c * 16 + srow) * HID_ + k0 + skoff;
            gld_lds16(ga, (char*)As + c * 1024);
            const unsigned short* gb = Wt + (size_t)(n0 + c * 16 + srow) * HID_ + k0 + skoff;
            gld_lds16(gb, (char*)Bs + c * 1024);
        }
        __syncthreads();   // compiler emits s_waitcnt vmcnt(0) before s_barrier

        s16x8 af[4], bf[4];
        #pragma unroll
        for (int r = 0; r < 4; ++r)
            af[r] = *(const s16x8*)((const char*)As + (wr + r * 16 + ln) * 64 + quad * 16);
        #pragma unroll
        for (int c = 0; c < 4; ++c)
            bf[c] = *(const s16x8*)((const char*)Bs + (wc + c * 16 + ln) * 64 + quad * 16);
        #pragma unroll
        for (int r = 0; r < 4; ++r)
            #pragma unroll
            for (int c = 0; c < 4; ++c)
                acc[r][c] = __builtin_amdgcn_mfma_f32_16x16x32_bf16(af[r], bf[c], acc[r][c], 0, 0, 0);
        __syncthreads();
    }

    // epilogue: C/D layout col=lane&15, row=quad*4+reg  [m89-verified]
    #pragma unroll
    for (int c = 0; c < 4; ++c) {
        const int col = n0 + wc + c * 16 + ln;
        const float bias = bq[col];
        #pragma unroll
        for (int r = 0; r < 4; ++r) {
            const int rowb = r0 + wr + r * 16 + quad * 4;
            #pragma unroll
            for (int e = 0; e < 4; ++e)
                Q[(size_t)(rowb + e) * HID_ + col] = acc[r][c][e] + bias;
        }
    }
}

// ---------------------------------------------------------------------------
// Kernel 2: per-(b,h) row stats. 192 blocks x 512 threads (thread = row i).
// ---------------------------------------------------------------------------
__launch_bounds__(512)
__global__ void rowstats(const float* __restrict__ Q, const float* __restrict__ prior,
                         const int* __restrict__ mask,
                         float* __restrict__ na_super, float* __restrict__ na_sub,
                         float* __restrict__ Ssum) {
    const int bh = blockIdx.x;
    const int b  = bh / NH_;
    const int h  = bh - b * NH_;
    const int i  = threadIdx.x;

    __shared__ float sh_s[M_];
    __shared__ float sh_pp[M_];
    __shared__ float sc[2][M_];

    float s = 0.f;
    if (i < M_ - 1) {
        const float4* qa = (const float4*)(Q + (size_t)(b * M_ + i)     * HID_ + h * HD_);
        const float4* qb = (const float4*)(Q + (size_t)(b * M_ + i + 1) * HID_ + h * HD_);
        #pragma unroll
        for (int t = 0; t < 16; ++t) {
            float4 x = qa[t], y = qb[t];
            s += x.x * y.x + x.y * y.y + x.z * y.z + x.w * y.w;
        }
        s *= (1.f / 64.f);
    }
    sh_s[i] = s;
    __syncthreads();

    const bool vp = (i > 0)      && (mask[b * M_ + i - 1] > 0);
    const bool vn = (i < M_ - 1) && (mask[b * M_ + i + 1] > 0);
    const float sp = vp ? sh_s[i - 1] : -1e30f;
    const float sn = vn ? s : -1e30f;
    const float mx = fmaxf(sp, sn);
    const float ep = vp ? __expf(sp - mx) : 0.f;
    const float en = vn ? __expf(sn - mx) : 0.f;
    float den = ep + en;
    den = (den > 0.f) ? den : 1.f;
    const float pp = ep / den;
    const float pn = en / den;
    sh_pp[i] = pp;
    __syncthreads();

    float Lv = 0.f;
    if (i < M_ - 1) {
        const float  sym = sqrtf(pn * sh_pp[i + 1] + 1e-4f);
        const size_t pb  = (size_t)b * (M_ * M_);
        const float  prs = prior[pb + (size_t)i * M_ + (i + 1)];
        const float  prb = prior[pb + (size_t)(i + 1) * M_ + i];
        const float  nsup = prs + (1.f - prs) * sym;
        na_super[bh * M_ + i] = nsup;
        na_sub[bh * M_ + i]   = prb + (1.f - prb) * sym;
        Lv = logf(nsup + 1e-9f);
    }

    // Hillis-Steele inclusive scan (double-buffered), then shift for exclusive
    int pbuf = 0;
    sc[0][i] = Lv;
    __syncthreads();
    for (int off = 1; off < M_; off <<= 1) {
        float v = sc[pbuf][i] + ((i >= off) ? sc[pbuf][i - off] : 0.f);
        sc[pbuf ^ 1][i] = v;
        __syncthreads();
        pbuf ^= 1;
    }
    Ssum[bh * M_ + i] = (i > 0) ? sc[pbuf][i - 1] : 0.f;
}

// ---------------------------------------------------------------------------
// Kernel 3: dense fill of both outputs. 256 threads = 2 rows x 512 cols.
// ---------------------------------------------------------------------------
__launch_bounds__(256)
__global__ void fill_out(const float* __restrict__ prior,
                         const float* __restrict__ na_super,
                         const float* __restrict__ na_sub,
                         const float* __restrict__ Ssum,
                         float* __restrict__ out) {
    const int tid = threadIdx.x;
    const int idx = blockIdx.x * 2 + (tid >> 7);       // 0..98303, order (b,i,h)
    const int h   = idx % NH_;
    const int tmp = idx / NH_;                         // b*512 + i
    const int i   = tmp & (M_ - 1);
    const int b   = tmp >> 9;
    const int bh  = b * NH_ + h;
    const int j0  = (tid & 127) * 4;

    const float4 pr4 = *(const float4*)(prior + (size_t)b * (M_ * M_) + (size_t)i * M_ + j0);
    const float4 S4  = *(const float4*)(Ssum + bh * M_ + j0);
    const float  Si  = Ssum[bh * M_ + i];
    const float  nsup_i   = (i < M_ - 1) ? na_super[bh * M_ + i]     : 0.f;
    const float  nsub_im1 = (i > 0)      ? na_sub[bh * M_ + i - 1]   : 0.f;

    const float c0 = 0.00999999977f;   // sqrtf(1e-4f), the off-neighbor V value

    const float pv[4] = {pr4.x, pr4.y, pr4.z, pr4.w};
    const float sv[4] = {S4.x, S4.y, S4.z, S4.w};
    float nav[4], ggv[4];
    #pragma unroll
    for (int e = 0; e < 4; ++e) {
        const int j = j0 + e;
        float na = fmaf(pv[e], 1.f - c0, c0);          // prior + (1-prior)*c0
        if (j == i - 1) na = nsub_im1;
        if (j == i + 1) na = nsup_i;
        const float d = sv[e] - Si;
        float g = __expf((j > i) ? d : -d) + 1e-4f;    // exp(S[max]-S[min]) + EPS
        if (j == i) g = na;                            // diag: neibor_attn[i,i]
        nav[e] = na;
        ggv[e] = g;
    }

    const size_t off  = ((size_t)(bh * M_ + i)) * M_ + j0;
    const size_t half = (size_t)B_ * NH_ * M_ * M_;    // 50331648
    f32x4 g4 = {ggv[0], ggv[1], ggv[2], ggv[3]};
    f32x4 n4 = {nav[0], nav[1], nav[2], nav[3]};
    __builtin_nontemporal_store(g4, (f32x4*)(out + off));         // g_attn
    __builtin_nontemporal_store(n4, (f32x4*)(out + half + off));  // neibor_attn
}

// ---------------------------------------------------------------------------
extern "C" void kernel_launch(void* const* d_in, const int* in_sizes, int n_in,
                              void* d_out, int out_size, void* d_ws, size_t ws_size,
                              hipStream_t stream) {
    const float* X     = (const float*)d_in[0];   // (B, M, HID)
    const float* prior = (const float*)d_in[1];   // (B, 1, M, M)
    const float* Wq    = (const float*)d_in[2];   // (HID, HID)
    const float* bq    = (const float*)d_in[3];   // (HID,)
    const int*   msk   = (const int*)  d_in[4];   // (B, M)
    float* out = (float*)d_out;

    // workspace layout: Q fp32 | na_super | na_sub | Ssum | Xb bf16 | Wt bf16 (~40 MB)
    float* Q        = (float*)d_ws;
    float* na_super = Q + (size_t)B_ * M_ * HID_;          // 6,291,456 floats
    float* na_sub   = na_super + (size_t)B_ * NH_ * M_;
    float* Ssum     = na_sub   + (size_t)B_ * NH_ * M_;
    unsigned short* Xb = (unsigned short*)(Ssum + (size_t)B_ * NH_ * M_);
    unsigned short* Wt = Xb + (size_t)B_ * M_ * HID_;

    convert_x<<<(B_ * M_ * HID_) / (256 * 8), 256, 0, stream>>>(X, Xb);
    transpose_w<<<dim3(HID_ / 32, HID_ / 32), 256, 0, stream>>>(Wq, Wt);

    dim3 gg(HID_ / 128, (B_ * M_) / 128);                  // (6, 64)
    gemm_qb<<<gg, 256, 0, stream>>>(Xb, Wt, bq, Q);

    rowstats<<<B_ * NH_, M_, 0, stream>>>(Q, prior, msk, na_super, na_sub, Ssum);

    fill_out<<<(B_ * NH_ * M_) / 2, 256, 0, stream>>>(prior, na_super, na_sub, Ssum, out);
}

// Round 4
// 467.066 us; speedup vs baseline: 1.1060x; 1.0378x over previous
//
#include <hip/hip_runtime.h>
#include <cstdint>
#include <cstddef>

// Problem constants (fixed by reference setup)
#define B_   16
#define M_   512
#define HID_ 768
#define NH_  12
#define HD_  64

typedef short s16x8 __attribute__((ext_vector_type(8)));
typedef float f32x4 __attribute__((ext_vector_type(4)));
typedef unsigned short u16x8 __attribute__((ext_vector_type(8)));
typedef unsigned short u16x4 __attribute__((ext_vector_type(4)));

__device__ __forceinline__ unsigned short f2bf(float f) {
    unsigned int u = __builtin_bit_cast(unsigned int, f);
    u = u + 0x7FFFu + ((u >> 16) & 1u);   // RNE truncate to bf16
    return (unsigned short)(u >> 16);
}

// async global->LDS, 16 B per lane; lds dest = wave-uniform base + lane*16
__device__ __forceinline__ void gld_lds16(const void* g, void* lds) {
    __builtin_amdgcn_global_load_lds(
        (const __attribute__((address_space(1))) unsigned int*)g,
        (__attribute__((address_space(3))) unsigned int*)lds,
        16, 0, 0);
}

// ---------------------------------------------------------------------------
// Pre-pass (fused): blocks [0,3072): X fp32 -> bf16 row-major (8 el/thread).
//                   blocks [3072,3648): W -> bf16 transposed Wt[n][k], 32x32.
// ---------------------------------------------------------------------------
__launch_bounds__(256)
__global__ void prep(const float* __restrict__ X, const float* __restrict__ W,
                     unsigned short* __restrict__ Xb, unsigned short* __restrict__ Wt) {
    __shared__ float T[32][33];
    const int blk = blockIdx.x;
    const int t   = threadIdx.x;
    if (blk < 3072) {
        const size_t i = ((size_t)blk * 256 + t) * 8;
        const float4 a = *(const float4*)(X + i);
        const float4 b = *(const float4*)(X + i + 4);
        u16x8 v = { f2bf(a.x), f2bf(a.y), f2bf(a.z), f2bf(a.w),
                    f2bf(b.x), f2bf(b.y), f2bf(b.z), f2bf(b.w) };
        *(u16x8*)(Xb + i) = v;
    } else {
        const int tb = blk - 3072;            // 0..575
        const int n0 = (tb % 24) * 32;
        const int k0 = (tb / 24) * 32;
        #pragma unroll
        for (int p = 0; p < 4; ++p) {
            const int r = p * 8 + (t >> 5);   // k_local
            const int c = t & 31;             // n_local
            T[r][c] = W[(size_t)(k0 + r) * HID_ + n0 + c];
        }
        __syncthreads();
        const int nl = t >> 3;                // 0..31
        const int k4 = (t & 7) * 4;
        u16x4 v = { f2bf(T[k4 + 0][nl]), f2bf(T[k4 + 1][nl]),
                    f2bf(T[k4 + 2][nl]), f2bf(T[k4 + 3][nl]) };
        *(u16x4*)(Wt + (size_t)(n0 + nl) * HID_ + k0 + k4) = v;
    }
}

// ---------------------------------------------------------------------------
// Kernel 1: Q = X @ Wq + bq  via bf16 MFMA 16x16x32, m97-style DMA staging.
// Tile 128x128, BK=32, 4 waves. A: Xb[M][K], B: Wt[N][K] (bf16 row-major,
// 64 B per K-tile row, unpadded -- required by global_load_lds lane layout).
// ---------------------------------------------------------------------------
__launch_bounds__(256)
__global__ void gemm_qb(const unsigned short* __restrict__ Xb,
                        const unsigned short* __restrict__ Wt,
                        const float* __restrict__ bq, float* __restrict__ Q) {
    __shared__ unsigned short As[128 * 32];   // row*64B + kbyte
    __shared__ unsigned short Bs[128 * 32];

    const int tid  = threadIdx.x;
    const int lane = tid & 63;
    const int wave = tid >> 6;
    const int wr   = (wave >> 1) * 64;
    const int wc   = (wave & 1) * 64;
    const int ln   = lane & 15;
    const int quad = lane >> 4;
    const int r0   = blockIdx.y * 128;
    const int n0   = blockIdx.x * 128;

    // staging geometry: chunk = 16 rows = 1024 B; lane -> row lane>>2, 16B piece lane&3
    const int srow  = lane >> 2;
    const int skoff = (lane & 3) * 8;         // bf16 elems within 32-elem row

    f32x4 acc[4][4] = {};

    for (int kt = 0; kt < HID_ / 32; ++kt) {
        const int k0 = kt * 32;
        #pragma unroll
        for (int c = wave * 2; c < wave * 2 + 2; ++c) {
            const unsigned short* ga = Xb + (size_t)(r0 + c * 16 + srow) * HID_ + k0 + skoff;
            gld_lds16(ga, (char*)As + c * 1024);
            const unsigned short* gb = Wt + (size_t)(n0 + c * 16 + srow) * HID_ + k0 + skoff;
            gld_lds16(gb, (char*)Bs + c * 1024);
        }
        __syncthreads();   // compiler emits s_waitcnt vmcnt(0) before s_barrier

        s16x8 af[4], bf[4];
        #pragma unroll
        for (int r = 0; r < 4; ++r)
            af[r] = *(const s16x8*)((const char*)As + (wr + r * 16 + ln) * 64 + quad * 16);
        #pragma unroll
        for (int c = 0; c < 4; ++c)
            bf[c] = *(const s16x8*)((const char*)Bs + (wc + c * 16 + ln) * 64 + quad * 16);
        #pragma unroll
        for (int r = 0; r < 4; ++r)
            #pragma unroll
            for (int c = 0; c < 4; ++c)
                acc[r][c] = __builtin_amdgcn_mfma_f32_16x16x32_bf16(af[r], bf[c], acc[r][c], 0, 0, 0);
        __syncthreads();
    }

    // epilogue: C/D layout col=lane&15, row=quad*4+reg  [m89-verified]
    #pragma unroll
    for (int c = 0; c < 4; ++c) {
        const int col = n0 + wc + c * 16 + ln;
        const float bias = bq[col];
        #pragma unroll
        for (int r = 0; r < 4; ++r) {
            const int rowb = r0 + wr + r * 16 + quad * 4;
            #pragma unroll
            for (int e = 0; e < 4; ++e)
                Q[(size_t)(rowb + e) * HID_ + col] = acc[r][c][e] + bias;
        }
    }
}

// ---------------------------------------------------------------------------
// Kernel 2: per-(b,h) row stats. 192 blocks x 512 threads (thread = row i).
// Exclusive prefix sum of log(na_super+1e-9) via wave-shuffle scan (1 barrier)
// ---------------------------------------------------------------------------
__launch_bounds__(512)
__global__ void rowstats(const float* __restrict__ Q, const float* __restrict__ prior,
                         const int* __restrict__ mask,
                         float* __restrict__ na_super, float* __restrict__ na_sub,
                         float* __restrict__ Ssum) {
    const int bh = blockIdx.x;
    const int b  = bh / NH_;
    const int h  = bh - b * NH_;
    const int i  = threadIdx.x;
    const int lane = i & 63;
    const int wid  = i >> 6;

    __shared__ float sh_s[M_];
    __shared__ float sh_pp[M_];
    __shared__ float wsum[8];

    float s = 0.f;
    if (i < M_ - 1) {
        const float4* qa = (const float4*)(Q + (size_t)(b * M_ + i)     * HID_ + h * HD_);
        const float4* qb = (const float4*)(Q + (size_t)(b * M_ + i + 1) * HID_ + h * HD_);
        #pragma unroll
        for (int t = 0; t < 16; ++t) {
            float4 x = qa[t], y = qb[t];
            s += x.x * y.x + x.y * y.y + x.z * y.z + x.w * y.w;
        }
        s *= (1.f / 64.f);
    }
    sh_s[i] = s;
    __syncthreads();

    const bool vp = (i > 0)      && (mask[b * M_ + i - 1] > 0);
    const bool vn = (i < M_ - 1) && (mask[b * M_ + i + 1] > 0);
    const float sp = vp ? sh_s[i - 1] : -1e30f;
    const float sn = vn ? s : -1e30f;
    const float mx = fmaxf(sp, sn);
    const float ep = vp ? __expf(sp - mx) : 0.f;
    const float en = vn ? __expf(sn - mx) : 0.f;
    float den = ep + en;
    den = (den > 0.f) ? den : 1.f;
    const float pp = ep / den;
    const float pn = en / den;
    sh_pp[i] = pp;
    __syncthreads();

    float Lv = 0.f;
    if (i < M_ - 1) {
        const float  sym = sqrtf(pn * sh_pp[i + 1] + 1e-4f);
        const size_t pb  = (size_t)b * (M_ * M_);
        const float  prs = prior[pb + (size_t)i * M_ + (i + 1)];
        const float  prb = prior[pb + (size_t)(i + 1) * M_ + i];
        const float  nsup = prs + (1.f - prs) * sym;
        na_super[bh * M_ + i] = nsup;
        na_sub[bh * M_ + i]   = prb + (1.f - prb) * sym;
        Lv = logf(nsup + 1e-9f);
    }

    // inclusive wave-shuffle scan, then cross-wave offset, then make exclusive
    float v = Lv;
    #pragma unroll
    for (int off = 1; off < 64; off <<= 1) {
        float tt = __shfl_up(v, off, 64);
        if (lane >= off) v += tt;
    }
    if (lane == 63) wsum[wid] = v;
    __syncthreads();
    float base = 0.f;
    for (int w = 0; w < wid; ++w) base += wsum[w];
    Ssum[bh * M_ + i] = v + base - Lv;   // exclusive prefix
}

// ---------------------------------------------------------------------------
// Kernel 3: dense fill. Block = one (b, row-pair); loops over all 12 heads
// with the prior row held in registers (prior read ONCE from HBM).
// 4096 blocks x 256 threads; 96 KB stored per block, plain float4 stores.
// ---------------------------------------------------------------------------
__launch_bounds__(256)
__global__ void fill_out(const float* __restrict__ prior,
                         const float* __restrict__ na_super,
                         const float* __restrict__ na_sub,
                         const float* __restrict__ Ssum,
                         float* __restrict__ out) {
    const int tid = threadIdx.x;
    const int bi  = blockIdx.x;                 // b*256 + ipair
    const int b   = bi >> 8;
    const int i   = ((bi & 255) << 1) | (tid >> 7);
    const int j0  = (tid & 127) * 4;

    const float4 pr4 = *(const float4*)(prior + (size_t)b * (M_ * M_) + (size_t)i * M_ + j0);
    const float pv[4] = {pr4.x, pr4.y, pr4.z, pr4.w};
    const float c0 = 0.00999999977f;            // sqrtf(1e-4f)
    const size_t half = (size_t)B_ * NH_ * M_ * M_;

    #pragma unroll 2
    for (int h = 0; h < NH_; ++h) {
        const int bh = b * NH_ + h;
        const float4 S4 = *(const float4*)(Ssum + (size_t)bh * M_ + j0);
        const float  Si = Ssum[bh * M_ + i];
        const float  nsup_i   = (i < M_ - 1) ? na_super[bh * M_ + i]   : 0.f;
        const float  nsub_im1 = (i > 0)      ? na_sub[bh * M_ + i - 1] : 0.f;
        const float sv[4] = {S4.x, S4.y, S4.z, S4.w};

        float nav[4], ggv[4];
        #pragma unroll
        for (int e = 0; e < 4; ++e) {
            const int j = j0 + e;
            float na = fmaf(pv[e], 1.f - c0, c0);      // prior + (1-prior)*c0
            if (j == i - 1) na = nsub_im1;
            if (j == i + 1) na = nsup_i;
            const float d = sv[e] - Si;
            float g = __expf((j > i) ? d : -d) + 1e-4f;
            if (j == i) g = na;                        // diag: neibor_attn[i,i]
            nav[e] = na;
            ggv[e] = g;
        }

        const size_t off = ((size_t)(bh * M_ + i)) * M_ + j0;
        *(float4*)(out + off)        = make_float4(ggv[0], ggv[1], ggv[2], ggv[3]);
        *(float4*)(out + half + off) = make_float4(nav[0], nav[1], nav[2], nav[3]);
    }
}

// ---------------------------------------------------------------------------
extern "C" void kernel_launch(void* const* d_in, const int* in_sizes, int n_in,
                              void* d_out, int out_size, void* d_ws, size_t ws_size,
                              hipStream_t stream) {
    const float* X     = (const float*)d_in[0];   // (B, M, HID)
    const float* prior = (const float*)d_in[1];   // (B, 1, M, M)
    const float* Wq    = (const float*)d_in[2];   // (HID, HID)
    const float* bq    = (const float*)d_in[3];   // (HID,)
    const int*   msk   = (const int*)  d_in[4];   // (B, M)
    float* out = (float*)d_out;

    // workspace layout: Q fp32 | na_super | na_sub | Ssum | Xb bf16 | Wt bf16 (~40 MB)
    float* Q        = (float*)d_ws;
    float* na_super = Q + (size_t)B_ * M_ * HID_;
    float* na_sub   = na_super + (size_t)B_ * NH_ * M_;
    float* Ssum     = na_sub   + (size_t)B_ * NH_ * M_;
    unsigned short* Xb = (unsigned short*)(Ssum + (size_t)B_ * NH_ * M_);
    unsigned short* Wt = Xb + (size_t)B_ * M_ * HID_;

    prep<<<3072 + 576, 256, 0, stream>>>(X, Wq, Xb, Wt);

    dim3 gg(HID_ / 128, (B_ * M_) / 128);                  // (6, 64)
    gemm_qb<<<gg, 256, 0, stream>>>(Xb, Wt, bq, Q);

    rowstats<<<B_ * NH_, M_, 0, stream>>>(Q, prior, msk, na_super, na_sub, Ssum);

    fill_out<<<B_ * (M_ / 2), 256, 0, stream>>>(prior, na_super, na_sub, Ssum, out);
}